// Round 4
// baseline (186.698 us; speedup 1.0000x reference)
//
#include <hip/hip_runtime.h>
#include <hip/hip_bf16.h>

#define N 16384
#define D 128
#define RS 16                        // row splits
#define CT 64                        // col tiles of 256 (4 waves x 64 cols)
#define ROWS_PER_SPLIT (N / RS)      // 1024
#define ITERS (ROWS_PER_SPLIT / 16)  // 64

typedef __attribute__((ext_vector_type(8))) short bf16x8;
typedef __attribute__((ext_vector_type(4))) float f32x4;

// ---------------- Kernel A: normalize targets -> bf16 bn ----------------
__global__ __launch_bounds__(256) void knorm(const float* __restrict__ t,
                                             __hip_bfloat16* __restrict__ bn) {
    const int row  = blockIdx.x * 4 + (threadIdx.x >> 6);
    const int lane = threadIdx.x & 63;
    const float2 v = *(const float2*)(t + (size_t)row * D + lane * 2);
    float ss = v.x * v.x + v.y * v.y;
#pragma unroll
    for (int m = 1; m <= 32; m <<= 1) ss += __shfl_xor(ss, m, 64);
    const float inv = rsqrtf(ss);
    __hip_bfloat162 o;
    o.x = __float2bfloat16(v.x * inv);
    o.y = __float2bfloat16(v.y * inv);
    *(__hip_bfloat162*)(bn + (size_t)row * D + lane * 2) = o;
}

// ---------------- Kernel B: fused bn @ bn^T + per-column group-argmax ----------------
// grid = 1024 blocks (exactly 4/CU), 4 waves. XCD-local decode: all blocks on
// one XCD share row-split s -> per-XCD hot A-set 512 KB (L2-resident); all
// waves on a CU read the same A 4KB/iter -> L1 broadcast.
// Argmax packs (value, 8-bit group id) into one float: low mantissa byte = id.
__global__ __launch_bounds__(256, 4) void kargmax(const __hip_bfloat16* __restrict__ bn,
                                                  float* __restrict__ pval,
                                                  int* __restrict__ pcode) {
    const int tid  = threadIdx.x;
    const int lane = tid & 63;
    const int w    = tid >> 6;
    const int b    = blockIdx.x;
    const int k    = b >> 3;
    const int s    = (b & 7) + 8 * (k >> 6);   // same-XCD blocks share split
    const int ct   = k & 63;
    const int j0w  = ct * 256 + w * 64;
    const int rbase = s * ROWS_PER_SPLIT;

    const int lr = lane & 15;
    const int lk = lane >> 4;

    // persistent B fragments: 64 cols x 128 K (64 VGPRs)
    bf16x8 fb[4][4];
#pragma unroll
    for (int cs = 0; cs < 4; ++cs)
#pragma unroll
        for (int ks = 0; ks < 4; ++ks)
            fb[cs][ks] = *(const bf16x8*)(bn + (size_t)(j0w + cs * 16 + lr) * D + ks * 32 + lk * 8);

    const char* aptr = (const char*)bn + (size_t)(rbase + lr) * 256 + lk * 16;

    float mv[4];
#pragma unroll
    for (int cs = 0; cs < 4; ++cs) mv[cs] = -1e30f;
    unsigned gidxv = (unsigned)lk;     // group id = it*4 + lk  (0..255)

    const f32x4 z4 = {0.f, 0.f, 0.f, 0.f};
    bf16x8 faA[4], faB[4];

#define LOADF(buf, itv) do {                                        \
    const char* p_ = aptr + (size_t)(itv) * 4096;                   \
    buf[0] = *(const bf16x8*)(p_);                                  \
    buf[1] = *(const bf16x8*)(p_ + 64);                             \
    buf[2] = *(const bf16x8*)(p_ + 128);                            \
    buf[3] = *(const bf16x8*)(p_ + 192); } while (0)

#define COMPUTEF(buf, itv) do {                                                             \
    f32x4 acc[4];                                                                           \
    _Pragma("unroll")                                                                       \
    for (int cs = 0; cs < 4; ++cs) {                                                        \
        acc[cs] = __builtin_amdgcn_mfma_f32_16x16x32_bf16(buf[0], fb[cs][0], z4, 0, 0, 0);  \
        _Pragma("unroll")                                                                   \
        for (int ks = 1; ks < 4; ++ks)                                                      \
            acc[cs] = __builtin_amdgcn_mfma_f32_16x16x32_bf16(buf[ks], fb[cs][ks], acc[cs], 0, 0, 0); \
    }                                                                                       \
    const int r0_ = rbase + (itv) * 16;                                                     \
    if ((unsigned)(r0_ - j0w) < 64u) {                                                      \
        _Pragma("unroll")                                                                   \
        for (int cs = 0; cs < 4; ++cs)                                                      \
            if (r0_ == j0w + cs * 16) {                                                     \
                _Pragma("unroll")                                                           \
                for (int r = 0; r < 4; ++r)                                                 \
                    acc[cs][r] = (lk * 4 + r == lr) ? acc[cs][r] - 1.0f : acc[cs][r];       \
            }                                                                               \
    }                                                                                       \
    _Pragma("unroll")                                                                       \
    for (int cs = 0; cs < 4; ++cs) {                                                        \
        const float g_ = fmaxf(fmaxf(fmaxf(acc[cs][0], acc[cs][1]), acc[cs][2]), acc[cs][3]); \
        const unsigned gb_ = (__float_as_uint(g_) & 0xFFFFFF00u) | gidxv;                   \
        mv[cs] = fmaxf(mv[cs], __uint_as_float(gb_));                                       \
    }                                                                                       \
    gidxv += 4u; } while (0)

    LOADF(faA, 0);
    for (int it2 = 0; it2 < ITERS; it2 += 2) {
        LOADF(faB, it2 + 1);
        COMPUTEF(faA, it2);
        LOADF(faA, it2 + 2);   // final overshoot reads into pval region — allocated, unused
        COMPUTEF(faB, it2 + 1);
        __builtin_amdgcn_s_barrier();   // raw barrier: keep waves lockstep for L1 A-sharing
    }
#undef LOADF
#undef COMPUTEF

    // reduce across the 4 lk groups (packed fmax — id rides in low byte)
#pragma unroll
    for (int cs = 0; cs < 4; ++cs) {
        float v = mv[cs];
        v = fmaxf(v, __shfl_xor(v, 16, 64));
        v = fmaxf(v, __shfl_xor(v, 32, 64));
        if (lane < 16) {
            pval[(size_t)s * N + j0w + cs * 16 + lr]  = v;
            pcode[(size_t)s * N + j0w + cs * 16 + lr] = rbase + (int)(__float_as_uint(v) & 255u) * 4;
        }
    }
}

// ---------------- Kernel C: merge splits, re-rank 4 candidates in fp32, hinge ----------------
__global__ __launch_bounds__(256) void kloss(const float* __restrict__ q,
                                             const float* __restrict__ t,
                                             const float* __restrict__ pval,
                                             const int* __restrict__ pcode,
                                             float* __restrict__ bsum) {
    const int j    = blockIdx.x * 4 + (threadIdx.x >> 6);
    const int lane = threadIdx.x & 63;

    // merge the RS split winners (lane s holds split s)
    float v = -1e30f;
    int   c = 0;
    if (lane < RS) { v = pval[(size_t)lane * N + j]; c = pcode[(size_t)lane * N + j]; }
#pragma unroll
    for (int m = 1; m <= 8; m <<= 1) {
        const float ov = __shfl_xor(v, m, 64);
        const int   oc = __shfl_xor(c, m, 64);
        if (ov > v || (ov == v && oc < c)) { v = ov; c = oc; }
    }
    c = __shfl(c, 0, 64);

    const float2 qv = *(const float2*)(q + (size_t)j * D + lane * 2);
    const float2 tv = *(const float2*)(t + (size_t)j * D + lane * 2);
    float qq = qv.x * qv.x + qv.y * qv.y;
    float tt = tv.x * tv.x + tv.y * tv.y;
    float qt = qv.x * tv.x + qv.y * tv.y;
    float ww[4], wt[4], qw[4];
#pragma unroll
    for (int r = 0; r < 4; ++r) {
        const float2 wv = *(const float2*)(t + (size_t)(c + r) * D + lane * 2);
        ww[r] = wv.x * wv.x + wv.y * wv.y;
        wt[r] = wv.x * tv.x + wv.y * tv.y;
        qw[r] = wv.x * qv.x + wv.y * qv.y;
    }
#pragma unroll
    for (int m = 1; m <= 32; m <<= 1) {
        qq += __shfl_xor(qq, m, 64);
        tt += __shfl_xor(tt, m, 64);
        qt += __shfl_xor(qt, m, 64);
#pragma unroll
        for (int r = 0; r < 4; ++r) {
            ww[r] += __shfl_xor(ww[r], m, 64);
            wt[r] += __shfl_xor(wt[r], m, 64);
            qw[r] += __shfl_xor(qw[r], m, 64);
        }
    }
    const float pos = qt * rsqrtf(qq * tt);
    float best = -1e30f, neg = 0.f;
#pragma unroll
    for (int r = 0; r < 4; ++r) {
        float cr = wt[r] * rsqrtf(ww[r] * tt);
        if (c + r == j) cr -= 1.0f;              // diag candidate, matches sim - eye
        if (cr > best) { best = cr; neg = qw[r] * rsqrtf(qq * ww[r]); }
    }
    const float l = fmaxf(0.f, 1.0f - pos + neg);

    __shared__ float ls[4];
    if (lane == 0) ls[threadIdx.x >> 6] = l;
    __syncthreads();
    if (threadIdx.x == 0) bsum[blockIdx.x] = ls[0] + ls[1] + ls[2] + ls[3];
}

// ---------------- Kernel D: deterministic final mean ----------------
__global__ __launch_bounds__(256) void kfinal(const float* __restrict__ bsum,
                                              float* __restrict__ out) {
    float sum = 0.f;
    for (int i = threadIdx.x; i < N / 4; i += 256) sum += bsum[i];
#pragma unroll
    for (int m = 1; m <= 32; m <<= 1) sum += __shfl_xor(sum, m, 64);
    __shared__ float ws2[4];
    if ((threadIdx.x & 63) == 0) ws2[threadIdx.x >> 6] = sum;
    __syncthreads();
    if (threadIdx.x == 0) out[0] = (ws2[0] + ws2[1] + ws2[2] + ws2[3]) * (1.0f / N);
}

extern "C" void kernel_launch(void* const* d_in, const int* in_sizes, int n_in,
                              void* d_out, int out_size, void* d_ws, size_t ws_size,
                              hipStream_t stream) {
    const float* q = (const float*)d_in[0];
    const float* t = (const float*)d_in[1];
    char* ws = (char*)d_ws;

    __hip_bfloat16* bn = (__hip_bfloat16*)ws;                          // 4 MB (must stay first)
    float* pval = (float*)(ws + (size_t)N * D * 2);                    // 1 MB
    int*   pcode = (int*)(ws + (size_t)N * D * 2 + (size_t)RS * N * 4);// 1 MB
    float* bsum = (float*)(ws + (size_t)N * D * 2 + (size_t)2 * RS * N * 4); // 16 KB

    knorm<<<dim3(N / 4), dim3(256), 0, stream>>>(t, bn);
    kargmax<<<dim3(CT * RS), dim3(256), 0, stream>>>(bn, pval, pcode);
    kloss<<<dim3(N / 4), dim3(256), 0, stream>>>(q, t, pval, pcode, bsum);
    kfinal<<<dim3(1), dim3(256), 0, stream>>>(bsum, (float*)d_out);
}

// Round 5
// 133.054 us; speedup vs baseline: 1.4032x; 1.4032x over previous
//
#include <hip/hip_runtime.h>
#include <hip/hip_bf16.h>

#define N 16384
#define D 128
#define RS 16                       // row splits
#define CTILES 32                   // col tiles of 512 (4 waves x 128 cols)
#define ROWS_PER_SPLIT (N / RS)     // 1024
#define NSTAGE (ROWS_PER_SPLIT / 64) // 16 stages of 64 rows

typedef __attribute__((ext_vector_type(8))) short bf16x8;
typedef __attribute__((ext_vector_type(4))) float f32x4;

#define GLOBAL_AS __attribute__((address_space(1)))
#define LDS_AS __attribute__((address_space(3)))

// ---------------- Kernel A: normalize targets -> bf16 bn ----------------
__global__ __launch_bounds__(256) void knorm(const float* __restrict__ t,
                                             __hip_bfloat16* __restrict__ bn) {
    const int row  = blockIdx.x * 4 + (threadIdx.x >> 6);
    const int lane = threadIdx.x & 63;
    const float2 v = *(const float2*)(t + (size_t)row * D + lane * 2);
    float ss = v.x * v.x + v.y * v.y;
#pragma unroll
    for (int m = 1; m <= 32; m <<= 1) ss += __shfl_xor(ss, m, 64);
    const float inv = rsqrtf(ss);
    __hip_bfloat162 o;
    o.x = __float2bfloat16(v.x * inv);
    o.y = __float2bfloat16(v.y * inv);
    *(__hip_bfloat162*)(bn + (size_t)row * D + lane * 2) = o;
}

// ---------------- Kernel B: fused bn @ bn^T + per-column group-argmax ----------------
// 512 blocks x 4 waves. Wave w: cols [ct*512 + w*128, +128); rows [s*1024,(s+1)*1024)
// streamed through a triple-buffered 16KB LDS A-tile (64 rows/stage), counted vmcnt(4).
// fb[8][4] persistent (AGPR-backed). XCD decode: XCD x gets 8 ct x 8 s (3MB hot < L2).
__global__ __launch_bounds__(256, 2) void kargmax(const __hip_bfloat16* __restrict__ bn,
                                                  float* __restrict__ pval,
                                                  int* __restrict__ pcode) {
    __shared__ __align__(16) char lds[3 * 16384];

    const int tid  = threadIdx.x;
    const int lane = tid & 63;
    const int w    = tid >> 6;
    const int b    = blockIdx.x;
    const int x    = b & 7;          // XCD id (round-robin dispatch)
    const int i    = b >> 3;         // 0..63 within XCD
    const int ct   = (x >> 1) * 8 + (i & 7);     // 8 col-tiles per XCD-pair group
    const int s    = (x & 1) * 8 + (i >> 3);     // 8 splits per XCD
    const int j0w  = ct * 512 + w * 128;
    const int rbase = s * ROWS_PER_SPLIT;

    const int lr = lane & 15;
    const int lk = lane >> 4;

    // persistent B fragments: 128 cols x 128 K (128 regs -> AGPR-backed on gfx950)
    bf16x8 fb[8][4];
#pragma unroll
    for (int cs = 0; cs < 8; ++cs)
#pragma unroll
        for (int ks = 0; ks < 4; ++ks)
            fb[cs][ks] = *(const bf16x8*)(bn + (size_t)(j0w + cs * 16 + lr) * D + ks * 32 + lk * 8);

    const char* bnb = (const char*)bn;

    float mv[8];
#pragma unroll
    for (int cs = 0; cs < 8; ++cs) mv[cs] = -1e30f;

    // stage t: rows rbase + t*64 .. +63 -> buffer (t%3); source pre-swizzled so the
    // swizzled ds_read (chunk ^ (row&7)) spreads banks while LDS dest stays linear.
#define STAGE(t_) do {                                                          \
    const int r0s_ = rbase + (t_) * 64;                                         \
    char* dst0_ = lds + ((t_) % 3) * 16384;                                     \
    _Pragma("unroll")                                                           \
    for (int u_ = 0; u_ < 4; ++u_) {                                            \
        const int chunk_ = u_ * 256 + tid;                                      \
        const int row_   = chunk_ >> 4;                                         \
        const int cb_    = (chunk_ & 15) ^ (row_ & 7);                          \
        const void* src_ = bnb + (size_t)(r0s_ + row_) * 256 + cb_ * 16;        \
        __builtin_amdgcn_global_load_lds((const GLOBAL_AS void*)src_,           \
                                         (LDS_AS void*)(dst0_ + chunk_ * 16),   \
                                         16, 0, 0);                             \
    } } while (0)

    STAGE(0);
    STAGE(1);

    for (int t = 0; t < NSTAGE; ++t) {
        asm volatile("s_waitcnt vmcnt(4)" ::: "memory");   // stage t landed; t+1 in flight
        __builtin_amdgcn_s_barrier();
        __builtin_amdgcn_sched_barrier(0);
        STAGE(t + 2);   // t>=14 overshoots into pval scratch — allocated, never computed
        const char* cbase = lds + (t % 3) * 16384;
#pragma unroll
        for (int si = 0; si < 4; ++si) {
            bf16x8 fa[4];
#pragma unroll
            for (int ks = 0; ks < 4; ++ks)
                fa[ks] = *(const bf16x8*)(cbase + (si * 16 + lr) * 256 +
                                          (((ks * 4 + lk) ^ (lr & 7)) * 16));
            f32x4 acc[8];
            __builtin_amdgcn_s_setprio(1);
#pragma unroll
            for (int cs = 0; cs < 8; ++cs) {
                acc[cs] = __builtin_amdgcn_mfma_f32_16x16x32_bf16(
                    fa[0], fb[cs][0], (f32x4){0.f, 0.f, 0.f, 0.f}, 0, 0, 0);
#pragma unroll
                for (int ks = 1; ks < 4; ++ks)
                    acc[cs] = __builtin_amdgcn_mfma_f32_16x16x32_bf16(
                        fa[ks], fb[cs][ks], acc[cs], 0, 0, 0);
            }
            __builtin_amdgcn_s_setprio(0);
            const int itg = t * 4 + si;
            const int r0_ = rbase + itg * 16;
            if ((unsigned)(r0_ - j0w) < 128u) {          // wave-uniform diag fixup
#pragma unroll
                for (int cs = 0; cs < 8; ++cs)
                    if (r0_ == j0w + cs * 16) {
#pragma unroll
                        for (int r = 0; r < 4; ++r)
                            acc[cs][r] = (lk * 4 + r == lr) ? acc[cs][r] - 1.0f : acc[cs][r];
                    }
            }
            const unsigned gid = (unsigned)(itg * 4 + lk);   // 4-row group id, 0..255
#pragma unroll
            for (int cs = 0; cs < 8; ++cs) {
                const float g_ = fmaxf(fmaxf(acc[cs][0], acc[cs][1]),
                                       fmaxf(acc[cs][2], acc[cs][3]));
                const unsigned gb_ = (__float_as_uint(g_) & 0xFFFFFF00u) | gid;
                mv[cs] = fmaxf(mv[cs], __uint_as_float(gb_));
            }
        }
    }
#undef STAGE

    // reduce across the 4 lk groups (packed fmax — group id rides in low byte)
#pragma unroll
    for (int cs = 0; cs < 8; ++cs) {
        float v = mv[cs];
        v = fmaxf(v, __shfl_xor(v, 16, 64));
        v = fmaxf(v, __shfl_xor(v, 32, 64));
        if (lane < 16) {
            pval[(size_t)s * N + j0w + cs * 16 + lr]  = v;
            pcode[(size_t)s * N + j0w + cs * 16 + lr] =
                rbase + (int)(__float_as_uint(v) & 255u) * 4;
        }
    }
}

// ---------------- Kernel C: merge splits, re-rank 4 candidates in fp32, hinge ----------------
__global__ __launch_bounds__(256) void kloss(const float* __restrict__ q,
                                             const float* __restrict__ t,
                                             const float* __restrict__ pval,
                                             const int* __restrict__ pcode,
                                             float* __restrict__ bsum) {
    const int j    = blockIdx.x * 4 + (threadIdx.x >> 6);
    const int lane = threadIdx.x & 63;

    // merge the RS split winners (lane s holds split s)
    float v = -1e30f;
    int   c = 0;
    if (lane < RS) { v = pval[(size_t)lane * N + j]; c = pcode[(size_t)lane * N + j]; }
#pragma unroll
    for (int m = 1; m <= 8; m <<= 1) {
        const float ov = __shfl_xor(v, m, 64);
        const int   oc = __shfl_xor(c, m, 64);
        if (ov > v || (ov == v && oc < c)) { v = ov; c = oc; }
    }
    c = __shfl(c, 0, 64);

    const float2 qv = *(const float2*)(q + (size_t)j * D + lane * 2);
    const float2 tv = *(const float2*)(t + (size_t)j * D + lane * 2);
    float qq = qv.x * qv.x + qv.y * qv.y;
    float tt = tv.x * tv.x + tv.y * tv.y;
    float qt = qv.x * tv.x + qv.y * tv.y;
    float ww[4], wt[4], qw[4];
#pragma unroll
    for (int r = 0; r < 4; ++r) {
        const float2 wv = *(const float2*)(t + (size_t)(c + r) * D + lane * 2);
        ww[r] = wv.x * wv.x + wv.y * wv.y;
        wt[r] = wv.x * tv.x + wv.y * tv.y;
        qw[r] = wv.x * qv.x + wv.y * qv.y;
    }
#pragma unroll
    for (int m = 1; m <= 32; m <<= 1) {
        qq += __shfl_xor(qq, m, 64);
        tt += __shfl_xor(tt, m, 64);
        qt += __shfl_xor(qt, m, 64);
#pragma unroll
        for (int r = 0; r < 4; ++r) {
            ww[r] += __shfl_xor(ww[r], m, 64);
            wt[r] += __shfl_xor(wt[r], m, 64);
            qw[r] += __shfl_xor(qw[r], m, 64);
        }
    }
    const float pos = qt * rsqrtf(qq * tt);
    float best = -1e30f, neg = 0.f;
#pragma unroll
    for (int r = 0; r < 4; ++r) {
        float cr = wt[r] * rsqrtf(ww[r] * tt);
        if (c + r == j) cr -= 1.0f;              // diag candidate, matches sim - eye
        if (cr > best) { best = cr; neg = qw[r] * rsqrtf(qq * ww[r]); }
    }
    const float l = fmaxf(0.f, 1.0f - pos + neg);

    __shared__ float ls[4];
    if (lane == 0) ls[threadIdx.x >> 6] = l;
    __syncthreads();
    if (threadIdx.x == 0) bsum[blockIdx.x] = ls[0] + ls[1] + ls[2] + ls[3];
}

// ---------------- Kernel D: deterministic final mean ----------------
__global__ __launch_bounds__(256) void kfinal(const float* __restrict__ bsum,
                                              float* __restrict__ out) {
    float sum = 0.f;
    for (int i = threadIdx.x; i < N / 4; i += 256) sum += bsum[i];
#pragma unroll
    for (int m = 1; m <= 32; m <<= 1) sum += __shfl_xor(sum, m, 64);
    __shared__ float ws2[4];
    if ((threadIdx.x & 63) == 0) ws2[threadIdx.x >> 6] = sum;
    __syncthreads();
    if (threadIdx.x == 0) out[0] = (ws2[0] + ws2[1] + ws2[2] + ws2[3]) * (1.0f / N);
}

extern "C" void kernel_launch(void* const* d_in, const int* in_sizes, int n_in,
                              void* d_out, int out_size, void* d_ws, size_t ws_size,
                              hipStream_t stream) {
    const float* q = (const float*)d_in[0];
    const float* t = (const float*)d_in[1];
    char* ws = (char*)d_ws;

    __hip_bfloat16* bn = (__hip_bfloat16*)ws;                          // 4 MB (must stay first)
    float* pval = (float*)(ws + (size_t)N * D * 2);                    // 1 MB (also overshoot pad)
    int*   pcode = (int*)(ws + (size_t)N * D * 2 + (size_t)RS * N * 4);// 1 MB
    float* bsum = (float*)(ws + (size_t)N * D * 2 + (size_t)2 * RS * N * 4); // 16 KB

    knorm<<<dim3(N / 4), dim3(256), 0, stream>>>(t, bn);
    kargmax<<<dim3(CTILES * RS), dim3(256), 0, stream>>>(bn, pval, pcode);
    kloss<<<dim3(N / 4), dim3(256), 0, stream>>>(q, t, pval, pcode, bsum);
    kfinal<<<dim3(1), dim3(256), 0, stream>>>(bsum, (float*)d_out);
}